// Round 13
// baseline (18.802 us; speedup 1.0000x reference)
//
#include <hip/hip_runtime.h>

// LocalLinearLayer, SINGLE dispatch, CHANNEL-SPLIT blocks (32 ch each).
// out[b,o,c] = bias[o] + sum_{j=0..24} W[o, o+j] * xp[b, o+j, c]
// xp[q] = x[q] (q<12), x[q-12] (12<=q<4108), x[q-24] (q>=4108)
//
// Per 16-output tile at o0, kappa in [0,64):
//   out[o0+m'][c] = sum_kappa A[m'][kappa] * B[kappa][c]
//   A[m'][kappa] = W[o0+m', kappa-m'] (0<=kappa-m'<25 else 0)
//   B[kappa][c]  = xp[o0+kappa][c]
// Block = (tile of 128 outputs) x (one batch) x (32-channel half).
// Channel split is traffic-neutral (disjoint channel data; W-band re-read x2
// is L2-hit) but halves the block's serial chain -> finer phase interleave,
// lower VGPR, smaller ramp/tail. Everything else = R9 verbatim.

typedef __attribute__((ext_vector_type(8))) short short8;
typedef __attribute__((ext_vector_type(4))) float f32x4;

constexpr int Lseq = 4096;
constexpr int C    = 64;
constexpr int CH   = 32;           // channels per block
constexpr int WIN  = 25;
constexpr int PAD  = 12;
constexpr int O_B  = 128;          // outputs per block (4 waves x 2 tiles x 16)
constexpr int PWIN = 176;          // taps staged (128 + 48 halo)
constexpr int PLX  = 184;          // x_lds row stride (shorts); non-pow2 bank spread
constexpr int WROW = 28;           // w_band row stride (floats)
constexpr int NB   = 32;

__device__ __forceinline__ ushort f2bf(float f) {
    union { float f; uint u; } v; v.f = f;
    uint r = v.u + 0x7FFFu + ((v.u >> 16) & 1u);   // round-to-nearest-even
    return (ushort)(r >> 16);
}

__device__ __forceinline__ int tap_to_t(int q) {
    int t = (q < PAD) ? q : ((q < Lseq + PAD) ? q - PAD : q - 2 * PAD);
    return t > Lseq - 1 ? Lseq - 1 : t;   // clamped taps always meet zero weights
}

__global__ __launch_bounds__(256) void lll_cs(const float* __restrict__ x,
                                              const float* __restrict__ W,
                                              const float* __restrict__ bias,
                                              float* __restrict__ out) {
    __shared__ ushort x_lds[CH * PLX];       // 11.5 KB: x bf16, [channel][tap]
    __shared__ float  w_band[O_B * WROW];    // 14.3 KB: raw band rows, f32

    const int bid   = blockIdx.x;
    const int tile  = bid >> 6;              // tile-major: bid+-64 = halo neighbor,
    const int sub   = bid & 63;              //  64%8==0 -> same XCD slot
    const int b     = sub >> 1;
    const int chalf = sub & 1;               // which 32-channel half
    const int blk_o = tile * O_B;

    const int tid  = threadIdx.x;
    const int lane = tid & 63;
    const int w    = tid >> 6;
    const int m    = lane & 15;
    const int quad = lane >> 4;

    // ---- issue x global loads (HBM-critical stream); 176 units ----
    const bool hasx = tid < 8 * (PWIN / 8);  // (c8, tap-oct): 8 x 22
    const int c8 = tid & 7, p0 = (tid >> 3) * 8;
    const float4* xb = (const float4*)(x + (size_t)b * Lseq * C);
    float4 f[8];
    if (hasx) {
#pragma unroll
        for (int i = 0; i < 8; ++i)
            f[i] = xb[(size_t)tap_to_t(blk_o + p0 + i) * 16 + chalf * 8 + c8];
    }

    // ---- stage W band rows -> LDS, f32, per-row coalesced (mostly L2-hit) ----
    {
        const int row = tid >> 1, h = tid & 1;
        const float* wr = W + (size_t)(blk_o + row) * 4121 + h * 12;
        float v[13];
#pragma unroll
        for (int i = 0; i < 13; ++i) v[i] = wr[i];
        float* dst = &w_band[row * WROW + h * 12];
#pragma unroll
        for (int i = 0; i < 13; ++i) dst[i] = v[i];
    }

    // ---- pack x -> bf16, b128 LDS writes ----
    if (hasx) {
#pragma unroll
        for (int ch = 0; ch < 4; ++ch) {
            short8 pk;
#pragma unroll
            for (int i = 0; i < 8; ++i) {
                const float v = (ch == 0) ? f[i].x : (ch == 1) ? f[i].y
                              : (ch == 2) ? f[i].z : f[i].w;
                pk[i] = (short)f2bf(v);
            }
            *(short8*)&x_lds[(c8 * 4 + ch) * PLX + p0] = pk;
        }
    }
    __syncthreads();

    // ---- gather A-fragments from w_band (LDS), pack bf16 in registers ----
    short8 afrag[2][2];
#pragma unroll
    for (int it = 0; it < 2; ++it) {
        const int row = (w * 2 + it) * 16 + m;            // relative band row
#pragma unroll
        for (int cch = 0; cch < 2; ++cch) {
            const int j0 = cch * 32 + quad * 8 - m;
            short8 pk;
#pragma unroll
            for (int e = 0; e < 8; ++e) {
                const int j  = j0 + e;
                const int jc = min(max(j, 0), WIN - 1);
                const float g = w_band[row * WROW + jc];
                pk[e] = (short)f2bf((j == jc) ? g : 0.f);
            }
            afrag[it][cch] = pk;
        }
    }

    // ---- compute: 2 tiles/wave x 2 channel-groups; store ----
    float* ob = out + (size_t)b * Lseq * C;
#pragma unroll
    for (int it = 0; it < 2; ++it) {
        const int t16 = w * 2 + it;
        const int o0  = blk_o + t16 * 16;

        f32x4 acc[2];
        {
            const float4 bv = *((const float4*)(bias + o0) + quad);
            const float bb[4] = {bv.x, bv.y, bv.z, bv.w};
#pragma unroll
            for (int r = 0; r < 4; ++r)
#pragma unroll
                for (int g = 0; g < 2; ++g) acc[g][r] = bb[r];
        }

#pragma unroll
        for (int cch = 0; cch < 2; ++cch) {
            const int poff = t16 * 16 + cch * 32 + quad * 8;
#pragma unroll
            for (int g = 0; g < 2; ++g) {
                short8 bf = *(const short8*)&x_lds[(m + 16 * g) * PLX + poff];
                acc[g] = __builtin_amdgcn_mfma_f32_16x16x32_bf16(afrag[it][cch], bf,
                                                                 acc[g], 0, 0, 0);
            }
        }

#pragma unroll
        for (int g = 0; g < 2; ++g)
#pragma unroll
            for (int r = 0; r < 4; ++r)
                ob[(size_t)(o0 + quad * 4 + r) * C + chalf * CH + m + 16 * g]
                    = acc[g][r];
    }
}

extern "C" void kernel_launch(void* const* d_in, const int* in_sizes, int n_in,
                              void* d_out, int out_size, void* d_ws, size_t ws_size,
                              hipStream_t stream) {
    const float* x    = (const float*)d_in[0];
    const float* W    = (const float*)d_in[1];
    const float* bias = (const float*)d_in[2];
    float*       out  = (float*)d_out;

    lll_cs<<<(Lseq / O_B) * NB * 2, 256, 0, stream>>>(x, W, bias, out);  // 2048 blocks
}